// Round 1
// baseline (237.496 us; speedup 1.0000x reference)
//
#include <hip/hip_runtime.h>
#include <hip/hip_bf16.h>
#include <cstdint>

#define EPS 1e-5f
#define PATH_COEFF 0.04419417382415922f   // 1/sqrt(512)
#define CG110     0.5773502691896258f     // 1/sqrt(3)

typedef __bf16 v8bf __attribute__((ext_vector_type(8)));
typedef float  v4f  __attribute__((ext_vector_type(4)));

static __device__ __forceinline__ unsigned short f2bf(float x){
    unsigned int u = __builtin_bit_cast(unsigned int, x);
    u += 0x7fffu + ((u >> 16) & 1u);      // round-to-nearest-even
    return (unsigned short)(u >> 16);
}

// ---------------------------------------------------------------------------
// K0: Vt[k][w][p] (bf16) = we_w2[k, p*128 + w]  (k<64), b2[p*128+w] at k=64.
// grid 65*128 blocks x 256 thr. Reads strided (L2-absorbed), writes coalesced.
// ---------------------------------------------------------------------------
__global__ __launch_bounds__(256)
void k_convV(const float* __restrict__ w2, const float* __restrict__ b2,
             unsigned short* __restrict__ Vt)
{
    int k = blockIdx.x >> 7;
    int w = blockIdx.x & 127;
    int t = threadIdx.x;
    const float* src = (k < 64) ? (w2 + (size_t)k * 65536 + w) : (b2 + w);
    unsigned short* dst = Vt + ((size_t)(k * 128 + w) << 9);
    dst[t]       = f2bf(src[(size_t)t * 128]);
    dst[t + 256] = f2bf(src[(size_t)(t + 256) * 128]);
}

// ---------------------------------------------------------------------------
// K1: per-row prep. block = 1 wave (64 lanes) per row.
//  Ht[k][n] fp32 (k-major, row 64 = 1.0 for the bias fold)
//  Qb[n][512] bf16: p<256: PC*f_u*f_v ; p>=256: PC*CG*sum_i y_u,i y_v,i
// ---------------------------------------------------------------------------
__global__ __launch_bounds__(64)
void k_prep(const float* __restrict__ x, const float* __restrict__ lng,
            const float* __restrict__ lnb, const float* __restrict__ w1,
            unsigned short* __restrict__ Qb, float* __restrict__ Ht, int N)
{
    int row  = blockIdx.x;
    int lane = threadIdx.x;
    const float* xr = x + (size_t)row * 64;
    float f[16]; float mu = 0.f;
    #pragma unroll
    for (int u = 0; u < 16; ++u){ f[u] = xr[u]; mu += f[u]; }
    mu *= (1.f/16.f);
    float var = 0.f;
    #pragma unroll
    for (int u = 0; u < 16; ++u){ float d = f[u] - mu; var += d*d; }
    var *= (1.f/16.f);
    float inv = rsqrtf(var + EPS);
    float lnf[16];
    #pragma unroll
    for (int u = 0; u < 16; ++u) lnf[u] = (f[u]-mu)*inv*lng[u] + lnb[u];
    float h1 = 0.f;
    #pragma unroll
    for (int u = 0; u < 16; ++u) h1 += lnf[u] * w1[u*64 + lane];
    float h = h1 / (1.f + expf(-h1));              // silu
    Ht[(size_t)lane * N + row] = h;
    if (lane == 0) Ht[(size_t)64 * N + row] = 1.f;

    union { unsigned short qs[8]; uint4 v; } qu;
    #pragma unroll
    for (int j = 0; j < 8; ++j){
        int p = lane*8 + j;
        float q;
        if (p < 256){
            int u = p >> 4, v = p & 15;
            q = PATH_COEFF * f[u] * f[v];
        } else {
            int pp = p - 256;
            int u = pp >> 4, v = pp & 15;
            const float* ya = xr + 16 + u*3;
            const float* yb = xr + 16 + v*3;
            q = (PATH_COEFF * CG110) * (ya[0]*yb[0] + ya[1]*yb[1] + ya[2]*yb[2]);
        }
        qu.qs[j] = f2bf(q);
    }
    *(uint4*)(Qb + (size_t)row*512 + lane*8) = qu.v;
}

// ---------------------------------------------------------------------------
// K2: partial[kc][n][w] = sum_{k in chunk} H[n,k] * sum_p Q[n,p] V[k,p,w]
// block = 128 thr (2 waves). Block tile: 64 rows x 128 w; wave tile 64x64
// = 4x4 MFMA 16x16x32 tiles. A/B frags straight from global (L2-resident).
// Per-k fp32 temp accumulator folded with fp32 H -> master.
// ---------------------------------------------------------------------------
__global__ __launch_bounds__(128, 2)
void k_main(const unsigned short* __restrict__ Qb, const unsigned short* __restrict__ Vt,
            const float* __restrict__ Ht, float* __restrict__ partial, int N, int MB)
{
    int tid  = threadIdx.x;
    int lane = tid & 63, wv = tid >> 6;
    int quad = lane >> 4, l16 = lane & 15;
    int mb = blockIdx.x % MB, kc = blockIdx.x / MB;
    int rowbase = mb * 64, wbase = wv * 64;

    const unsigned short* ap = Qb + (size_t)(rowbase + l16) * 512 + quad * 8;

    v4f mast[4][4];
    #pragma unroll
    for (int m=0;m<4;++m)
      #pragma unroll
      for (int n=0;n<4;++n)
        #pragma unroll
        for (int r=0;r<4;++r) mast[m][n][r] = 0.f;

    for (int kk = 0; kk < 5; ++kk){
        int k = kc*5 + kk;
        const unsigned short* bp = Vt + (size_t)(k*128 + wbase + l16) * 512 + quad * 8;
        v4f tmp[4][4];
        #pragma unroll
        for (int m=0;m<4;++m)
          #pragma unroll
          for (int n=0;n<4;++n)
            #pragma unroll
            for (int r=0;r<4;++r) tmp[m][n][r] = 0.f;

        #pragma unroll 2
        for (int ps = 0; ps < 16; ++ps){
            int po = ps * 32;
            v8bf a[4], bb[4];
            #pragma unroll
            for (int m=0;m<4;++m) a[m]  = *(const v8bf*)(ap + (size_t)m*8192 + po);
            #pragma unroll
            for (int n=0;n<4;++n) bb[n] = *(const v8bf*)(bp + (size_t)n*8192 + po);
            #pragma unroll
            for (int m=0;m<4;++m)
              #pragma unroll
              for (int n=0;n<4;++n)
                tmp[m][n] = __builtin_amdgcn_mfma_f32_16x16x32_bf16(a[m], bb[n], tmp[m][n], 0, 0, 0);
        }
        // fold: master += H[row, k] * tmp   (C/D row = quad*4 + reg)
        const float* hp = Ht + (size_t)k*N + rowbase + quad*4;
        #pragma unroll
        for (int m=0;m<4;++m){
            v4f hv = *(const v4f*)(hp + m*16);
            #pragma unroll
            for (int n=0;n<4;++n)
              #pragma unroll
              for (int r=0;r<4;++r)
                mast[m][n][r] += hv[r] * tmp[m][n][r];
        }
    }
    float* pp = partial + (size_t)kc*N*128 + (size_t)(rowbase + quad*4)*128 + wbase + l16;
    #pragma unroll
    for (int m=0;m<4;++m)
      #pragma unroll
      for (int n=0;n<4;++n)
        #pragma unroll
        for (int r=0;r<4;++r)
          pp[(m*16 + r)*128 + n*16] = mast[m][n][r];
}

// ---------------------------------------------------------------------------
// K3: reduce 13 partials + LN(128) + silu(128->512) + dot(512) per row.
// block = 256 thr = 8 rows x 32-lane crews.
// ---------------------------------------------------------------------------
__global__ __launch_bounds__(256)
void k_final(const float* __restrict__ partial, const float* __restrict__ lng,
             const float* __restrict__ lnb, const float* __restrict__ w1,
             const float* __restrict__ w2, const float* __restrict__ b2,
             float* __restrict__ out, int N)
{
    __shared__ float lnf_s[8][128];
    int tid  = threadIdx.x;
    int crew = tid & 31, rl = tid >> 5;
    int row  = blockIdx.x*8 + rl;

    float tpv[4]; float sum = 0.f, sumsq = 0.f;
    #pragma unroll
    for (int i=0;i<4;++i){
        int w = crew + 32*i;
        const float* p0 = partial + (size_t)row*128 + w;
        float t = 0.f;
        #pragma unroll
        for (int s=0;s<13;++s) t += p0[(size_t)s*N*128];
        tpv[i] = t; sum += t; sumsq += t*t;
    }
    #pragma unroll
    for (int off=16; off>0; off>>=1){
        sum   += __shfl_down(sum,   off, 32);
        sumsq += __shfl_down(sumsq, off, 32);
    }
    sum = __shfl(sum, 0, 32); sumsq = __shfl(sumsq, 0, 32);
    float mu  = sum * (1.f/128.f);
    float var = sumsq * (1.f/128.f) - mu*mu;
    float inv = rsqrtf(var + EPS);
    #pragma unroll
    for (int i=0;i<4;++i){
        int w = crew + 32*i;
        lnf_s[rl][w] = (tpv[i]-mu)*inv*lng[w] + lnb[w];
    }
    __syncthreads();

    float accout = 0.f;
    for (int pass=0; pass<4; ++pass){
        int j0 = (crew + pass*32) * 4;
        float a0=0.f, a1=0.f, a2=0.f, a3=0.f;
        for (int w=0; w<128; ++w){
            float lf = lnf_s[rl][w];
            const float4 wvv = *(const float4*)(w1 + (size_t)w*512 + j0);
            a0 += lf*wvv.x; a1 += lf*wvv.y; a2 += lf*wvv.z; a3 += lf*wvv.w;
        }
        const float4 w2v = *(const float4*)(w2 + j0);
        accout += (a0/(1.f+expf(-a0)))*w2v.x;
        accout += (a1/(1.f+expf(-a1)))*w2v.y;
        accout += (a2/(1.f+expf(-a2)))*w2v.z;
        accout += (a3/(1.f+expf(-a3)))*w2v.w;
    }
    #pragma unroll
    for (int off=16; off>0; off>>=1) accout += __shfl_down(accout, off, 32);
    if (crew == 0) out[row] = accout + b2[0];
}

// ---------------------------------------------------------------------------
extern "C" void kernel_launch(void* const* d_in, const int* in_sizes, int n_in,
                              void* d_out, int out_size, void* d_ws, size_t ws_size,
                              hipStream_t stream)
{
    const float* x     = (const float*)d_in[0];
    const float* we_g  = (const float*)d_in[1];
    const float* we_b  = (const float*)d_in[2];
    const float* we_w1 = (const float*)d_in[3];
    const float* we_w2 = (const float*)d_in[4];
    const float* we_b2 = (const float*)d_in[5];
    const float* om_g  = (const float*)d_in[6];
    const float* om_b  = (const float*)d_in[7];
    const float* om_w1 = (const float*)d_in[8];
    const float* om_w2 = (const float*)d_in[9];
    const float* om_b2 = (const float*)d_in[10];

    int N  = in_sizes[0] / 64;     // 2048
    int MB = N / 64;               // 32 row-blocks

    char* ws = (char*)d_ws;
    size_t offV = 0;
    size_t szV  = (size_t)65*128*512*2;          // 8,519,680 B
    size_t offQ = offV + szV;
    size_t szQ  = (size_t)N*512*2;               // 2 MB
    size_t offH = offQ + szQ;
    size_t szH  = (size_t)65*N*4;                // 520 KB
    size_t offP = offH + szH;                    // 13*N*128*4 = 13 MB

    unsigned short* Vt = (unsigned short*)(ws + offV);
    unsigned short* Qb = (unsigned short*)(ws + offQ);
    float* Ht  = (float*)(ws + offH);
    float* Par = (float*)(ws + offP);
    float* out = (float*)d_out;

    hipLaunchKernelGGL(k_convV, dim3(65*128), dim3(256), 0, stream, we_w2, we_b2, Vt);
    hipLaunchKernelGGL(k_prep,  dim3(N),      dim3(64),  0, stream, x, we_g, we_b, we_w1, Qb, Ht, N);
    hipLaunchKernelGGL(k_main,  dim3(13*MB),  dim3(128), 0, stream, Qb, Vt, Ht, Par, N, MB);
    hipLaunchKernelGGL(k_final, dim3(N/8),    dim3(256), 0, stream, Par, om_g, om_b, om_w1, om_w2, om_b2, out, N);
}

// Round 2
// 150.381 us; speedup vs baseline: 1.5793x; 1.5793x over previous
//
#include <hip/hip_runtime.h>
#include <hip/hip_bf16.h>
#include <cstdint>

#define EPS 1e-5f
#define PATH_COEFF 0.04419417382415922f   // 1/sqrt(512)
#define CG110     0.5773502691896258f     // 1/sqrt(3)

typedef __bf16 v8bf __attribute__((ext_vector_type(8)));
typedef float  v4f  __attribute__((ext_vector_type(4)));

static __device__ __forceinline__ unsigned short f2bf(float x){
    unsigned int u = __builtin_bit_cast(unsigned int, x);
    u += 0x7fffu + ((u >> 16) & 1u);      // RNE
    return (unsigned short)(u >> 16);
}
static __device__ __forceinline__ unsigned short f2h(float x){
    return __builtin_bit_cast(unsigned short, (_Float16)x);
}
static __device__ __forceinline__ float h2f(unsigned short b){
    return (float)__builtin_bit_cast(_Float16, b);
}

// ---------------------------------------------------------------------------
// K0a: Vt2 frag-major: Vt2[k][ps(16)][quad(4)][w(128)][8p] bf16
//   element (k, p, w) -> ps=p>>5, quad=(p>>3)&3, j=p&7
// grid 65 k x 4 p-slabs(128); block 256. Coalesced reads, LDS tile, full-line writes.
// ---------------------------------------------------------------------------
__global__ __launch_bounds__(256)
void k_convV(const float* __restrict__ w2, const float* __restrict__ b2,
             unsigned short* __restrict__ Vt2)
{
    __shared__ unsigned short tile[32][128];   // [p_local][w]
    int k    = blockIdx.x / 4;
    int slab = blockIdx.x & 3;
    int t    = threadIdx.x;
    const float* srcbase = (k < 64) ? (w2 + (size_t)k * 65536) : b2;

    for (int chunk = 0; chunk < 4; ++chunk){
        int pbase = slab*128 + chunk*32;
        // load 32 p x 128 w floats, coalesced float4
        #pragma unroll
        for (int i = 0; i < 4; ++i){
            int g = t + 256*i;            // float4 index in chunk
            int ploc = g >> 5, c4 = g & 31;
            const float4 v = *(const float4*)(srcbase + (size_t)(pbase + ploc)*128 + c4*4);
            unsigned int w0 = (unsigned)f2bf(v.x) | ((unsigned)f2bf(v.y) << 16);
            unsigned int w1 = (unsigned)f2bf(v.z) | ((unsigned)f2bf(v.w) << 16);
            *(uint2*)&tile[ploc][c4*4] = make_uint2(w0, w1);
        }
        __syncthreads();
        // write: thread (w, h): p window [chunk*32 + h*16, +16) -> quads 2h,2h+1
        int w = t & 127, h = t >> 7;
        int ps = slab*4 + chunk;
        unsigned int words[8];
        #pragma unroll
        for (int g2 = 0; g2 < 8; ++g2)
            words[g2] = (unsigned)tile[h*16 + g2*2][w] | ((unsigned)tile[h*16 + g2*2 + 1][w] << 16);
        unsigned short* dq0 = Vt2 + (((size_t)(k*16 + ps)*4 + 2*h    )*128 + w)*8;
        unsigned short* dq1 = Vt2 + (((size_t)(k*16 + ps)*4 + 2*h + 1)*128 + w)*8;
        *(uint4*)dq0 = make_uint4(words[0], words[1], words[2], words[3]);
        *(uint4*)dq1 = make_uint4(words[4], words[5], words[6], words[7]);
        __syncthreads();
    }
}

// ---------------------------------------------------------------------------
// K0b: w1t[j(512)][w(128)] bf16 = om_w1[w][j]. grid 4 j-slabs x 256 thr.
// ---------------------------------------------------------------------------
__global__ __launch_bounds__(256)
void k_convW(const float* __restrict__ w1, unsigned short* __restrict__ w1t)
{
    __shared__ unsigned short tile[32][128];   // [w_local][j_local]
    int j0 = blockIdx.x * 128;
    int t  = threadIdx.x;
    for (int chunk = 0; chunk < 4; ++chunk){
        #pragma unroll
        for (int i = 0; i < 4; ++i){
            int g = t + 256*i;
            int wloc = g >> 5, c4 = g & 31;
            int w = chunk*32 + wloc;
            const float4 v = *(const float4*)(w1 + (size_t)w*512 + j0 + c4*4);
            unsigned int a = (unsigned)f2bf(v.x) | ((unsigned)f2bf(v.y) << 16);
            unsigned int b = (unsigned)f2bf(v.z) | ((unsigned)f2bf(v.w) << 16);
            *(uint2*)&tile[wloc][c4*4] = make_uint2(a, b);
        }
        __syncthreads();
        int jl = t & 127, h = t >> 7;
        unsigned int words[8];
        #pragma unroll
        for (int g2 = 0; g2 < 8; ++g2)
            words[g2] = (unsigned)tile[h*16 + g2*2][jl] | ((unsigned)tile[h*16 + g2*2 + 1][jl] << 16);
        unsigned short* dst = w1t + (size_t)(j0 + jl)*128 + chunk*32 + h*16;
        *(uint4*)dst       = make_uint4(words[0], words[1], words[2], words[3]);
        *(uint4*)(dst + 8) = make_uint4(words[4], words[5], words[6], words[7]);
        __syncthreads();
    }
}

// ---------------------------------------------------------------------------
// K1: per-row prep. 1 wave per row.
//  Ht[k][n] fp32 (row 64 = 1.0 bias fold)
//  Q2 frag-major: Q2[rb(row/64)][ps][quad][r64][8p] bf16
// ---------------------------------------------------------------------------
__global__ __launch_bounds__(64)
void k_prep(const float* __restrict__ x, const float* __restrict__ lng,
            const float* __restrict__ lnb, const float* __restrict__ w1,
            unsigned short* __restrict__ Q2, float* __restrict__ Ht, int N)
{
    int row  = blockIdx.x;
    int lane = threadIdx.x;
    const float* xr = x + (size_t)row * 64;
    float f[16]; float mu = 0.f;
    #pragma unroll
    for (int u = 0; u < 16; ++u){ f[u] = xr[u]; mu += f[u]; }
    mu *= (1.f/16.f);
    float var = 0.f;
    #pragma unroll
    for (int u = 0; u < 16; ++u){ float d = f[u] - mu; var += d*d; }
    var *= (1.f/16.f);
    float inv = rsqrtf(var + EPS);
    float lnf[16];
    #pragma unroll
    for (int u = 0; u < 16; ++u) lnf[u] = (f[u]-mu)*inv*lng[u] + lnb[u];
    float h1 = 0.f;
    #pragma unroll
    for (int u = 0; u < 16; ++u) h1 += lnf[u] * w1[u*64 + lane];
    float h = h1 / (1.f + expf(-h1));
    Ht[(size_t)lane * N + row] = h;
    if (lane == 0) Ht[(size_t)64 * N + row] = 1.f;

    union { unsigned short qs[8]; uint4 v; } qu;
    #pragma unroll
    for (int j = 0; j < 8; ++j){
        int p = lane*8 + j;
        float q;
        if (p < 256){
            int u = p >> 4, v = p & 15;
            q = PATH_COEFF * f[u] * f[v];
        } else {
            int pp = p - 256;
            int u = pp >> 4, v = pp & 15;
            const float* ya = xr + 16 + u*3;
            const float* yb = xr + 16 + v*3;
            q = (PATH_COEFF * CG110) * (ya[0]*yb[0] + ya[1]*yb[1] + ya[2]*yb[2]);
        }
        qu.qs[j] = f2bf(q);
    }
    int rb = row >> 6, r64 = row & 63;
    int ps = lane >> 2, quad = lane & 3;
    *(uint4*)(Q2 + (((size_t)(rb*16 + ps)*4 + quad)*64 + r64)*8) = qu.v;
}

// ---------------------------------------------------------------------------
// K2: partial[k][n][w] (fp16) = H[n,k] * sum_p Q[n,p] V[k,p,w]
// One k per block. Block 256 thr = 4 waves (2x2), tile 128 rows x 128 w;
// wave tile 64x64 = 4x4 MFMA 16x16x32. Frag-major loads = 1KiB/wave-instr.
// ---------------------------------------------------------------------------
__global__ __launch_bounds__(256, 4)
void k_main(const unsigned short* __restrict__ Q2, const unsigned short* __restrict__ Vt2,
            const float* __restrict__ Ht, unsigned short* __restrict__ partial, int N)
{
    int tid  = threadIdx.x;
    int lane = tid & 63, wv = tid >> 6;
    int r2 = wv >> 1, c2 = wv & 1;
    int quad = lane >> 4, l16 = lane & 15;
    int mb = blockIdx.x / 65, kb = blockIdx.x % 65;
    int rowbase = mb*128 + r2*64;
    int rb = rowbase >> 6;
    int wbase = c2*64;

    const unsigned short* aroot = Q2  + (size_t)rb*32768 + quad*512  + l16*8;
    const unsigned short* broot = Vt2 + (size_t)kb*65536 + quad*1024 + (wbase + l16)*8;

    v4f acc[4][4];
    #pragma unroll
    for (int m=0;m<4;++m)
      #pragma unroll
      for (int n=0;n<4;++n)
        #pragma unroll
        for (int r=0;r<4;++r) acc[m][n][r] = 0.f;

    #pragma unroll 4
    for (int ps = 0; ps < 16; ++ps){
        const unsigned short* ap = aroot + ps*2048;
        const unsigned short* bp = broot + ps*4096;
        v8bf a[4], bb[4];
        #pragma unroll
        for (int m=0;m<4;++m) a[m]  = *(const v8bf*)(ap + m*128);
        #pragma unroll
        for (int n=0;n<4;++n) bb[n] = *(const v8bf*)(bp + n*128);
        #pragma unroll
        for (int m=0;m<4;++m)
          #pragma unroll
          for (int n=0;n<4;++n)
            acc[m][n] = __builtin_amdgcn_mfma_f32_16x16x32_bf16(a[m], bb[n], acc[m][n], 0, 0, 0);
    }

    const float* hp = Ht + (size_t)kb*N + rowbase + quad*4;
    unsigned short* pp = partial + (size_t)kb*N*128 + ((size_t)rowbase + quad*4)*128 + wbase + l16;
    #pragma unroll
    for (int m=0;m<4;++m){
        v4f hv = *(const v4f*)(hp + m*16);
        #pragma unroll
        for (int n=0;n<4;++n)
          #pragma unroll
          for (int r=0;r<4;++r)
            pp[(size_t)(m*16 + r)*128 + n*16] = f2h(hv[r]*acc[m][n][r]);
    }
}

// ---------------------------------------------------------------------------
// K3: reduce 65 fp16 slices + LayerNorm(128) -> lnf bf16[row][128]
// block = 128 thr = one row (2 waves).
// ---------------------------------------------------------------------------
__global__ __launch_bounds__(128)
void k_red(const unsigned short* __restrict__ partial, const float* __restrict__ g,
           const float* __restrict__ b, unsigned short* __restrict__ lnf, int N)
{
    int row = blockIdx.x, t = threadIdx.x;
    const unsigned short* p0 = partial + (size_t)row*128 + t;
    float s = 0.f;
    #pragma unroll
    for (int sl = 0; sl < 65; ++sl) s += h2f(p0[(size_t)sl*N*128]);
    float a = s, q = s*s;
    #pragma unroll
    for (int off = 32; off > 0; off >>= 1){
        a += __shfl_down(a, off, 64);
        q += __shfl_down(q, off, 64);
    }
    __shared__ float red[4];
    int wv = t >> 6;
    if ((t & 63) == 0){ red[wv*2] = a; red[wv*2+1] = q; }
    __syncthreads();
    float sum = red[0] + red[2], sumsq = red[1] + red[3];
    float mu  = sum * (1.f/128.f);
    float var = sumsq * (1.f/128.f) - mu*mu;
    float inv = rsqrtf(var + EPS);
    lnf[(size_t)row*128 + t] = f2bf((s - mu)*inv*g[t] + b[t]);
}

// ---------------------------------------------------------------------------
// K4: out[n] = silu(lnf @ om_w1) @ om_w2 + om_b2  via MFMA (M=N rows, K=128, N=512)
// block 128 thr = 2 waves; tile 64 rows x 128 j; atomicAdd partial row sums.
// ---------------------------------------------------------------------------
__global__ __launch_bounds__(128)
void k_mlp2(const unsigned short* __restrict__ lnf, const unsigned short* __restrict__ w1t,
            const float* __restrict__ w2, const float* __restrict__ b2,
            float* __restrict__ out, int N)
{
    int tid = threadIdx.x, lane = tid & 63, wv = tid >> 6;
    int quad = lane >> 4, l16 = lane & 15;
    int MB = N >> 6;
    int mb = blockIdx.x % MB, jb = blockIdx.x / MB;
    int rowbase = mb*64, jbase = jb*128 + wv*64;

    v4f acc[4][4];
    #pragma unroll
    for (int m=0;m<4;++m)
      #pragma unroll
      for (int n=0;n<4;++n)
        #pragma unroll
        for (int r=0;r<4;++r) acc[m][n][r] = 0.f;

    #pragma unroll
    for (int ps = 0; ps < 4; ++ps){
        v8bf a[4], bb[4];
        #pragma unroll
        for (int m=0;m<4;++m)
            a[m]  = *(const v8bf*)(lnf + (size_t)(rowbase + m*16 + l16)*128 + ps*32 + quad*8);
        #pragma unroll
        for (int n=0;n<4;++n)
            bb[n] = *(const v8bf*)(w1t + (size_t)(jbase + n*16 + l16)*128 + ps*32 + quad*8);
        #pragma unroll
        for (int m=0;m<4;++m)
          #pragma unroll
          for (int n=0;n<4;++n)
            acc[m][n] = __builtin_amdgcn_mfma_f32_16x16x32_bf16(a[m], bb[n], acc[m][n], 0, 0, 0);
    }

    float w2v[4];
    #pragma unroll
    for (int n=0;n<4;++n) w2v[n] = w2[jbase + n*16 + l16];

    bool first = (jb == 0) && (wv == 0);
    #pragma unroll
    for (int m=0;m<4;++m){
        #pragma unroll
        for (int r=0;r<4;++r){
            float ssum = 0.f;
            #pragma unroll
            for (int n=0;n<4;++n){
                float v = acc[m][n][r];
                ssum += (v / (1.f + expf(-v))) * w2v[n];
            }
            #pragma unroll
            for (int off=8; off>0; off>>=1) ssum += __shfl_xor(ssum, off, 64);
            if (l16 == 0){
                float add = ssum + (first ? b2[0] : 0.f);
                atomicAdd(&out[rowbase + m*16 + quad*4 + r], add);
            }
        }
    }
}

// ---------------------------------------------------------------------------
extern "C" void kernel_launch(void* const* d_in, const int* in_sizes, int n_in,
                              void* d_out, int out_size, void* d_ws, size_t ws_size,
                              hipStream_t stream)
{
    const float* x     = (const float*)d_in[0];
    const float* we_g  = (const float*)d_in[1];
    const float* we_b  = (const float*)d_in[2];
    const float* we_w1 = (const float*)d_in[3];
    const float* we_w2 = (const float*)d_in[4];
    const float* we_b2 = (const float*)d_in[5];
    const float* om_g  = (const float*)d_in[6];
    const float* om_b  = (const float*)d_in[7];
    const float* om_w1 = (const float*)d_in[8];
    const float* om_w2 = (const float*)d_in[9];
    const float* om_b2 = (const float*)d_in[10];

    int N  = in_sizes[0] / 64;     // 2048

    char* ws = (char*)d_ws;
    size_t offV = 0;
    size_t szV  = (size_t)65*16*4*128*8*2;       // 8,519,680
    size_t offQ = offV + szV;
    size_t szQ  = (size_t)N*512*2;               // 2 MB
    size_t offH = offQ + szQ;
    size_t szH  = (size_t)65*N*4;
    size_t offP = offH + szH;
    size_t szP  = (size_t)65*N*128*2;            // 34 MB fp16
    size_t offL = offP + szP;
    size_t szL  = (size_t)N*128*2;
    size_t offW = offL + szL;                    // +128 KB

    unsigned short* Vt2 = (unsigned short*)(ws + offV);
    unsigned short* Q2  = (unsigned short*)(ws + offQ);
    float* Ht           = (float*)(ws + offH);
    unsigned short* Par = (unsigned short*)(ws + offP);
    unsigned short* Lnf = (unsigned short*)(ws + offL);
    unsigned short* W1t = (unsigned short*)(ws + offW);
    float* out = (float*)d_out;

    hipMemsetAsync(d_out, 0, (size_t)N*4, stream);
    hipLaunchKernelGGL(k_convV, dim3(65*4),      dim3(256), 0, stream, we_w2, we_b2, Vt2);
    hipLaunchKernelGGL(k_convW, dim3(4),         dim3(256), 0, stream, om_w1, W1t);
    hipLaunchKernelGGL(k_prep,  dim3(N),         dim3(64),  0, stream, x, we_g, we_b, we_w1, Q2, Ht, N);
    hipLaunchKernelGGL(k_main,  dim3((N/128)*65),dim3(256), 0, stream, Q2, Vt2, Ht, Par, N);
    hipLaunchKernelGGL(k_red,   dim3(N),         dim3(128), 0, stream, Par, om_g, om_b, Lnf, N);
    hipLaunchKernelGGL(k_mlp2,  dim3((N/64)*4),  dim3(128), 0, stream, Lnf, W1t, om_w2, om_b2, out, N);
}